// Round 8
// baseline (275.902 us; speedup 1.0000x reference)
//
#include <hip/hip_runtime.h>

#define DEMB 128

typedef __attribute__((ext_vector_type(8))) _Float16 half8;
typedef __attribute__((ext_vector_type(4))) _Float16 half4;
typedef __attribute__((ext_vector_type(4))) float f32x4;

// ---------- Ms[l] = gcn_l @ lin_l (row-major), grid L*128, block 128
__global__ void kwc(const float* __restrict__ gcn, const float* __restrict__ lin,
                    float* __restrict__ Ms) {
  __shared__ float sa[128];
  int l = blockIdx.x >> 7, i = blockIdx.x & 127, j = threadIdx.x;
  sa[j] = gcn[((size_t)l * 128 + i) * 128 + j];
  __syncthreads();
  float acc = 0.f;
#pragma unroll 8
  for (int k = 0; k < 128; ++k) acc += sa[k] * lin[((size_t)l * 128 + k) * 128 + j];
  Ms[((size_t)l * 128 + i) * 128 + j] = acc;
}

// ---------- stage 2: A1 = M1@M0, B1 = M3@M2, v0 = M1@b0, cC = M3@b2
__global__ void kst2(const float* __restrict__ Ms, const float* __restrict__ gb,
                     float* __restrict__ A1, float* __restrict__ B1,
                     float* __restrict__ v0, float* __restrict__ cb) {
  const float* M0 = Ms;
  const float* M1 = Ms + 16384;
  const float* M2 = Ms + 2 * 16384;
  const float* M3 = Ms + 3 * 16384;
  __shared__ float sa[128];
  int b = blockIdx.x, j = threadIdx.x;
  if (b < 128) {
    sa[j] = M1[b * 128 + j];
    __syncthreads();
    float acc = 0.f;
#pragma unroll 8
    for (int k = 0; k < 128; ++k) acc += sa[k] * M0[k * 128 + j];
    A1[b * 128 + j] = acc;
  } else if (b < 256) {
    int i = b - 128;
    sa[j] = M3[i * 128 + j];
    __syncthreads();
    float acc = 0.f;
#pragma unroll 8
    for (int k = 0; k < 128; ++k) acc += sa[k] * M2[k * 128 + j];
    B1[i * 128 + j] = acc;
  } else if (b == 256) {
    sa[j] = gb[j];
    __syncthreads();
    float acc = 0.f;
#pragma unroll 8
    for (int k = 0; k < 128; ++k) acc += M1[j * 128 + k] * sa[k];
    v0[j] = acc;
  } else {
    sa[j] = gb[2 * 128 + j];
    __syncthreads();
    float acc = 0.f;
#pragma unroll 8
    for (int k = 0; k < 128; ++k) acc += M3[j * 128 + k] * sa[k];
    cb[256 + j] = acc;  // cC
  }
}

// ---------- stage 3: Rh = fp16(B1@A1) row-major [c][k], cA = B1@v0, cB = B1@b1
__global__ void kst3(const float* __restrict__ A1, const float* __restrict__ B1,
                     const float* __restrict__ v0, const float* __restrict__ gb,
                     _Float16* __restrict__ Rh, float* __restrict__ cb) {
  __shared__ float sa[128];
  int b = blockIdx.x, j = threadIdx.x;
  if (b < 128) {
    sa[j] = B1[b * 128 + j];
    __syncthreads();
    float acc = 0.f;
#pragma unroll 8
    for (int k = 0; k < 128; ++k) acc += sa[k] * A1[k * 128 + j];
    Rh[b * 128 + j] = (_Float16)acc;
  } else if (b == 128) {
    sa[j] = v0[j];
    __syncthreads();
    float acc = 0.f;
#pragma unroll 8
    for (int k = 0; k < 128; ++k) acc += B1[j * 128 + k] * sa[k];
    cb[j] = acc;  // cA
  } else {
    sa[j] = gb[128 + j];
    __syncthreads();
    float acc = 0.f;
#pragma unroll 8
    for (int k = 0; k < 128; ++k) acc += B1[j * 128 + k] * sa[k];
    cb[128 + j] = acc;  // cB
  }
}

// ---------- graph prep
__global__ void kdeg(const int* __restrict__ ei, int* __restrict__ deg, int etot) {
  int i = blockIdx.x * 256 + threadIdx.x;
  if (i < etot) atomicAdd(&deg[ei[etot + i]], 1);
}

// scan step 1 (+ dinv/dinv2, self-loop +1 folded)
__global__ void kscan1(const int* __restrict__ deg, int* __restrict__ off,
                       int* __restrict__ bsum, float* __restrict__ dinv,
                       float* __restrict__ dinv2, int n) {
  __shared__ int s[256];
  int t = threadIdx.x, i = blockIdx.x * 256 + t;
  int c = 0;
  if (i < n) {
    c = deg[i];
    float dv = rsqrtf((float)(c + 1));
    dinv[i] = dv;
    dinv2[i] = dv * dv;
  }
  s[t] = c;
  __syncthreads();
  for (int o = 1; o < 256; o <<= 1) {
    int v = (t >= o) ? s[t - o] : 0;
    __syncthreads();
    s[t] += v;
    __syncthreads();
  }
  if (i < n) off[i] = s[t] - c;
  if (t == 255) bsum[blockIdx.x] = s[t];
}

__global__ void kscan2(const int* __restrict__ bsum, int* __restrict__ boff,
                       int nb, int* __restrict__ off, int n, int etot) {
  __shared__ int s[256];
  int t = threadIdx.x;
  int c = (t < nb) ? bsum[t] : 0;
  s[t] = c;
  __syncthreads();
  for (int o = 1; o < 256; o <<= 1) {
    int v = (t >= o) ? s[t - o] : 0;
    __syncthreads();
    s[t] += v;
    __syncthreads();
  }
  if (t < nb) boff[t] = s[t] - c;
  if (t == 0) off[n] = etot;
}

__global__ void kscan3(int* __restrict__ off, const int* __restrict__ boff,
                       int* __restrict__ cur, int n) {
  int i = blockIdx.x * 256 + threadIdx.x;
  if (i < n) {
    int o = off[i] + boff[i >> 8];
    off[i] = o;
    cur[i] = o;
  }
}

__global__ void kfill(const int* __restrict__ ei, int* __restrict__ cur,
                      int* __restrict__ csr, int etot) {
  int i = blockIdx.x * 256 + threadIdx.x;
  if (i < etot) {
    int d = ei[etot + i];
    int p = atomicAdd(&cur[d], 1);
    csr[p] = ei[i];
  }
}

// ---------- prescale: xh[i][c] = fp16(x[i][c] * dinv[i])
__global__ void kpre(const float* __restrict__ x, const float* __restrict__ dinv,
                     _Float16* __restrict__ xh, int n) {
  int gid = blockIdx.x * 256 + threadIdx.x;
  if (gid >= n * 32) return;
  int r = gid >> 5, c = (gid & 31) * 4;
  float d = dinv[r];
  float4 v = *(const float4*)(x + (size_t)r * DEMB + c);
  half4 o = {(_Float16)(v.x * d), (_Float16)(v.y * d), (_Float16)(v.z * d), (_Float16)(v.w * d)};
  *(half4*)(xh + (size_t)r * DEMB + c) = o;
}

// ---------- fp16 aggregation: quarter-wave (16 lanes) per node, 16-deep clamped bursts.
// vout[i] = fp16( scale[i] * (vin[i] + sum_src vin[src]) )
// WITHU: also u = dinv[i]*(a_in[i] + sum_src a_in[src]); u_out[i]=u; a_out[i]=dinv[i]*u
template <int WITHU>
__launch_bounds__(256)
__global__ void kagg16(const _Float16* __restrict__ vin, const int* __restrict__ csr,
                       const int* __restrict__ off, const float* __restrict__ scale,
                       const float* __restrict__ dinv, const float* __restrict__ a_in,
                       float* __restrict__ u_out, float* __restrict__ a_out,
                       _Float16* __restrict__ vout, int n) {
  int node = (int)((blockIdx.x * 256u + threadIdx.x) >> 4);
  if (node >= n) return;
  int l16 = threadIdx.x & 15;
  const _Float16* base = vin + 8 * l16;
  half8 sv = *(const half8*)(base + (size_t)node * DEMB);
  float acc[8];
#pragma unroll
  for (int j = 0; j < 8; ++j) acc[j] = (float)sv[j];
  float s = WITHU ? a_in[node] : 0.f;
  int e = off[node], end = off[node + 1];
  while (e < end) {
    int em = end - 1;
    int idx[16];
    float wgt[16];
#pragma unroll
    for (int j = 0; j < 16; ++j) {
      int ee = e + j;
      idx[j] = csr[min(ee, em)];
      wgt[j] = (ee < end) ? 1.f : 0.f;
    }
    half8 r[16];
#pragma unroll
    for (int j = 0; j < 16; ++j) r[j] = *(const half8*)(base + (size_t)idx[j] * DEMB);
    if (WITHU) {
#pragma unroll
      for (int j = 0; j < 16; ++j) s += wgt[j] * a_in[idx[j]];
    }
#pragma unroll
    for (int j = 0; j < 16; ++j) {
#pragma unroll
      for (int q = 0; q < 8; ++q) acc[q] += wgt[j] * (float)r[j][q];
    }
    e += 16;
  }
  float sc = scale[node];
  half8 o;
#pragma unroll
  for (int j = 0; j < 8; ++j) o[j] = (_Float16)(acc[j] * sc);
  *(half8*)(vout + (size_t)node * DEMB + 8 * l16) = o;
  if (WITHU && l16 == 0) {
    float dv = dinv[node];
    float u = dv * s;
    u_out[node] = u;
    a_out[node] = dv * u;
  }
}

// ---------- final MFMA GEMM: out[r][c] = sum_k y[r][k]*Rh[c][k]
//            + u3[r]*cb[c] + u2[r]*cb[128+c] + u1[r]*cb[256+c] + b3[c]
__launch_bounds__(256)
__global__ void kgemm16(const _Float16* __restrict__ y, const _Float16* __restrict__ Rh,
                        const float* __restrict__ u1, const float* __restrict__ u2,
                        const float* __restrict__ u3, const float* __restrict__ cb,
                        const float* __restrict__ b3, float* __restrict__ out, int n) {
  int t = threadIdx.x;
  int wv = t >> 6, lane = t & 63;
  int l16 = lane & 15, g = lane >> 4;
  int row0 = blockIdx.x * 128 + wv * 32;
  f32x4 acc[2][8];
#pragma unroll
  for (int w = 0; w < 2; ++w)
#pragma unroll
    for (int n8 = 0; n8 < 8; ++n8) acc[w][n8] = (f32x4){0.f, 0.f, 0.f, 0.f};

#pragma unroll
  for (int k0 = 0; k0 < 128; k0 += 32) {
    half8 a0 = *(const half8*)(y + (size_t)(row0 + l16) * DEMB + k0 + g * 8);
    half8 a1 = *(const half8*)(y + (size_t)(row0 + 16 + l16) * DEMB + k0 + g * 8);
#pragma unroll
    for (int n8 = 0; n8 < 8; ++n8) {
      half8 b = *(const half8*)(Rh + (size_t)(n8 * 16 + l16) * DEMB + k0 + g * 8);
      acc[0][n8] = __builtin_amdgcn_mfma_f32_16x16x32_f16(a0, b, acc[0][n8], 0, 0, 0);
      acc[1][n8] = __builtin_amdgcn_mfma_f32_16x16x32_f16(a1, b, acc[1][n8], 0, 0, 0);
    }
  }
#pragma unroll
  for (int n8 = 0; n8 < 8; ++n8) {
    int col = n8 * 16 + l16;
    float cA = cb[col], cB = cb[128 + col], cC = cb[256 + col], bb = b3[col];
#pragma unroll
    for (int w = 0; w < 2; ++w)
#pragma unroll
      for (int r = 0; r < 4; ++r) {
        int row = row0 + w * 16 + g * 4 + r;
        if (row < n) {
          out[(size_t)row * DEMB + col] =
              acc[w][n8][r] + u3[row] * cA + u2[row] * cB + u1[row] * cC + bb;
        }
      }
  }
}

extern "C" void kernel_launch(void* const* d_in, const int* in_sizes, int n_in,
                              void* d_out, int out_size, void* d_ws, size_t ws_size,
                              hipStream_t stream) {
  const float* x0 = (const float*)d_in[0];
  const int* ei = (const int*)d_in[1];
  const float* lin = (const float*)d_in[2];
  const float* gcn = (const float*)d_in[3];
  const float* gb = (const float*)d_in[4];
  float* out = (float*)d_out;

  int N = in_sizes[0] / DEMB;
  int E = in_sizes[1] / 2;
  int L = in_sizes[2] / (DEMB * DEMB);  // = 4
  int NP = (N + 127) & ~127;

  char* w = (char*)d_ws;
  auto carve = [&](size_t bytes) {
    char* p = w;
    w += (bytes + 255) & ~(size_t)255;
    return p;
  };
  float* Ms    = (float*)carve((size_t)L * DEMB * DEMB * 4);
  float* A1    = (float*)carve((size_t)DEMB * DEMB * 4);
  float* B1    = (float*)carve((size_t)DEMB * DEMB * 4);
  _Float16* Rh = (_Float16*)carve((size_t)DEMB * DEMB * 2);
  float* v0    = (float*)carve((size_t)DEMB * 4);
  float* cb    = (float*)carve((size_t)3 * DEMB * 4);
  float* dinv  = (float*)carve((size_t)N * 4);
  float* dnv2  = (float*)carve((size_t)N * 4);
  int* deg     = (int*)carve((size_t)N * 4);
  int* off     = (int*)carve((size_t)(N + 1) * 4);
  int* cur     = (int*)carve((size_t)N * 4);
  int* bsum    = (int*)carve(256 * 4);
  int* boff    = (int*)carve(256 * 4);
  int* csr     = (int*)carve((size_t)E * 4);
  float* u1    = (float*)carve((size_t)N * 4);
  float* u2    = (float*)carve((size_t)N * 4);
  float* u3    = (float*)carve((size_t)N * 4);
  float* a1    = (float*)carve((size_t)N * 4);
  float* a2    = (float*)carve((size_t)N * 4);
  float* a3    = (float*)carve((size_t)N * 4);
  _Float16* ha = (_Float16*)carve((size_t)NP * DEMB * 2);
  _Float16* hb = (_Float16*)carve((size_t)NP * DEMB * 2);
  (void)ws_size; (void)n_in; (void)out_size;

  int nbN = (N + 255) / 256;
  int nbE = (E + 255) / 256;
  int nbA = (N * 16 + 255) / 256;  // agg: 16 threads per node

  // zero degree counters
  hipMemsetAsync(deg, 0, (size_t)N * 4, stream);

  // weight/bias precompute (3 launches)
  kwc<<<L * DEMB, DEMB, 0, stream>>>(gcn, lin, Ms);
  kst2<<<258, DEMB, 0, stream>>>(Ms, gb, A1, B1, v0, cb);
  kst3<<<130, DEMB, 0, stream>>>(A1, B1, v0, gb, Rh, cb);

  // graph prep (5 launches)
  kdeg<<<nbE, 256, 0, stream>>>(ei, deg, E);
  kscan1<<<nbN, 256, 0, stream>>>(deg, off, bsum, dinv, dnv2, N);
  kscan2<<<1, 256, 0, stream>>>(bsum, boff, nbN, off, N, E);
  kscan3<<<nbN, 256, 0, stream>>>(off, boff, cur, N);
  kfill<<<nbE, 256, 0, stream>>>(ei, cur, csr, E);

  // prescale + 4 chained fp16 aggregations with fused u-chain
  kpre<<<(N * 32 + 255) / 256, 256, 0, stream>>>(x0, dinv, ha, N);
  kagg16<1><<<nbA, 256, 0, stream>>>(ha, csr, off, dnv2, dinv, dinv, u1, a1, hb, N);
  kagg16<1><<<nbA, 256, 0, stream>>>(hb, csr, off, dnv2, dinv, a1, u2, a2, ha, N);
  kagg16<1><<<nbA, 256, 0, stream>>>(ha, csr, off, dnv2, dinv, a2, u3, a3, hb, N);
  kagg16<0><<<nbA, 256, 0, stream>>>(hb, csr, off, dinv, dinv, nullptr, nullptr, nullptr, ha, N);

  // final fp16-MFMA GEMM with rank-1 bias terms -> fp32 out
  kgemm16<<<(N + 127) / 128, 256, 0, stream>>>(ha, Rh, u1, u2, u3, cb, gb + 3 * DEMB, out, N);
}

// Round 9
// 233.325 us; speedup vs baseline: 1.1825x; 1.1825x over previous
//
#include <hip/hip_runtime.h>

#define DEMB 128

typedef __attribute__((ext_vector_type(8))) _Float16 half8;
typedef __attribute__((ext_vector_type(4))) _Float16 half4;
typedef __attribute__((ext_vector_type(4))) float f32x4;

// ---------- Ms[l] = gcn_l @ lin_l (row-major), grid L*128, block 128
__global__ void kwc(const float* __restrict__ gcn, const float* __restrict__ lin,
                    float* __restrict__ Ms) {
  __shared__ float sa[128];
  int l = blockIdx.x >> 7, i = blockIdx.x & 127, j = threadIdx.x;
  sa[j] = gcn[((size_t)l * 128 + i) * 128 + j];
  __syncthreads();
  float acc = 0.f;
#pragma unroll 8
  for (int k = 0; k < 128; ++k) acc += sa[k] * lin[((size_t)l * 128 + k) * 128 + j];
  Ms[((size_t)l * 128 + i) * 128 + j] = acc;
}

// ---------- stage 2: A1 = M1@M0, B1 = M3@M2, v0 = M1@b0, cC = M3@b2
__global__ void kst2(const float* __restrict__ Ms, const float* __restrict__ gb,
                     float* __restrict__ A1, float* __restrict__ B1,
                     float* __restrict__ v0, float* __restrict__ cb) {
  const float* M0 = Ms;
  const float* M1 = Ms + 16384;
  const float* M2 = Ms + 2 * 16384;
  const float* M3 = Ms + 3 * 16384;
  __shared__ float sa[128];
  int b = blockIdx.x, j = threadIdx.x;
  if (b < 128) {
    sa[j] = M1[b * 128 + j];
    __syncthreads();
    float acc = 0.f;
#pragma unroll 8
    for (int k = 0; k < 128; ++k) acc += sa[k] * M0[k * 128 + j];
    A1[b * 128 + j] = acc;
  } else if (b < 256) {
    int i = b - 128;
    sa[j] = M3[i * 128 + j];
    __syncthreads();
    float acc = 0.f;
#pragma unroll 8
    for (int k = 0; k < 128; ++k) acc += sa[k] * M2[k * 128 + j];
    B1[i * 128 + j] = acc;
  } else if (b == 256) {
    sa[j] = gb[j];
    __syncthreads();
    float acc = 0.f;
#pragma unroll 8
    for (int k = 0; k < 128; ++k) acc += M1[j * 128 + k] * sa[k];
    v0[j] = acc;
  } else {
    sa[j] = gb[2 * 128 + j];
    __syncthreads();
    float acc = 0.f;
#pragma unroll 8
    for (int k = 0; k < 128; ++k) acc += M3[j * 128 + k] * sa[k];
    cb[256 + j] = acc;  // cC
  }
}

// ---------- stage 3: Rh = fp16(B1@A1) row-major [c][k], cA = B1@v0, cB = B1@b1
__global__ void kst3(const float* __restrict__ A1, const float* __restrict__ B1,
                     const float* __restrict__ v0, const float* __restrict__ gb,
                     _Float16* __restrict__ Rh, float* __restrict__ cb) {
  __shared__ float sa[128];
  int b = blockIdx.x, j = threadIdx.x;
  if (b < 128) {
    sa[j] = B1[b * 128 + j];
    __syncthreads();
    float acc = 0.f;
#pragma unroll 8
    for (int k = 0; k < 128; ++k) acc += sa[k] * A1[k * 128 + j];
    Rh[b * 128 + j] = (_Float16)acc;
  } else if (b == 128) {
    sa[j] = v0[j];
    __syncthreads();
    float acc = 0.f;
#pragma unroll 8
    for (int k = 0; k < 128; ++k) acc += B1[j * 128 + k] * sa[k];
    cb[j] = acc;  // cA
  } else {
    sa[j] = gb[128 + j];
    __syncthreads();
    float acc = 0.f;
#pragma unroll 8
    for (int k = 0; k < 128; ++k) acc += B1[j * 128 + k] * sa[k];
    cb[128 + j] = acc;  // cB
  }
}

// ---------- graph prep
__global__ void kdeg(const int* __restrict__ ei, int* __restrict__ deg, int etot) {
  int i = blockIdx.x * 256 + threadIdx.x;
  if (i < etot) atomicAdd(&deg[ei[etot + i]], 1);
}

// scan step 1 (+ dinv/dinv2, self-loop +1 folded)
__global__ void kscan1(const int* __restrict__ deg, int* __restrict__ off,
                       int* __restrict__ bsum, float* __restrict__ dinv,
                       float* __restrict__ dinv2, int n) {
  __shared__ int s[256];
  int t = threadIdx.x, i = blockIdx.x * 256 + t;
  int c = 0;
  if (i < n) {
    c = deg[i];
    float dv = rsqrtf((float)(c + 1));
    dinv[i] = dv;
    dinv2[i] = dv * dv;
  }
  s[t] = c;
  __syncthreads();
  for (int o = 1; o < 256; o <<= 1) {
    int v = (t >= o) ? s[t - o] : 0;
    __syncthreads();
    s[t] += v;
    __syncthreads();
  }
  if (i < n) off[i] = s[t] - c;
  if (t == 255) bsum[blockIdx.x] = s[t];
}

__global__ void kscan2(const int* __restrict__ bsum, int* __restrict__ boff,
                       int nb, int* __restrict__ off, int n, int etot) {
  __shared__ int s[256];
  int t = threadIdx.x;
  int c = (t < nb) ? bsum[t] : 0;
  s[t] = c;
  __syncthreads();
  for (int o = 1; o < 256; o <<= 1) {
    int v = (t >= o) ? s[t - o] : 0;
    __syncthreads();
    s[t] += v;
    __syncthreads();
  }
  if (t < nb) boff[t] = s[t] - c;
  if (t == 0) off[n] = etot;
}

__global__ void kscan3(int* __restrict__ off, const int* __restrict__ boff,
                       int* __restrict__ cur, int n) {
  int i = blockIdx.x * 256 + threadIdx.x;
  if (i < n) {
    int o = off[i] + boff[i >> 8];
    off[i] = o;
    cur[i] = o;
  }
}

__global__ void kfill(const int* __restrict__ ei, int* __restrict__ cur,
                      int* __restrict__ csr, int etot) {
  int i = blockIdx.x * 256 + threadIdx.x;
  if (i < etot) {
    int d = ei[etot + i];
    int p = atomicAdd(&cur[d], 1);
    csr[p] = ei[i];
  }
}

// ---------- prescale: xh[i][c] = fp16(x[i][c] * dinv[i])
__global__ void kpre(const float* __restrict__ x, const float* __restrict__ dinv,
                     _Float16* __restrict__ xh, int n) {
  int gid = blockIdx.x * 256 + threadIdx.x;
  if (gid >= n * 32) return;
  int r = gid >> 5, c = (gid & 31) * 4;
  float d = dinv[r];
  float4 v = *(const float4*)(x + (size_t)r * DEMB + c);
  half4 o = {(_Float16)(v.x * d), (_Float16)(v.y * d), (_Float16)(v.z * d), (_Float16)(v.w * d)};
  *(half4*)(xh + (size_t)r * DEMB + c) = o;
}

// ---------- fp16 aggregation: quarter-wave (16 lanes) per node, 8/4/tail ladder.
// __launch_bounds__(256, 8) pins VGPR <= 64 (occupancy cliff; R8 showed 68 VGPR @ 21% occ).
// vout[i] = fp16( scale[i] * (vin[i] + sum_src vin[src]) )
// WITHU: also u = dinv[i]*(a_in[i] + sum_src a_in[src]); u_out[i]=u; a_out[i]=dinv[i]*u
template <int WITHU>
__launch_bounds__(256, 8)
__global__ void kagg16(const _Float16* __restrict__ vin, const int* __restrict__ csr,
                       const int* __restrict__ off, const float* __restrict__ scale,
                       const float* __restrict__ dinv, const float* __restrict__ a_in,
                       float* __restrict__ u_out, float* __restrict__ a_out,
                       _Float16* __restrict__ vout, int n) {
  int node = (int)((blockIdx.x * 256u + threadIdx.x) >> 4);
  if (node >= n) return;
  int l16 = threadIdx.x & 15;
  const _Float16* base = vin + 8 * l16;
  half8 sv = *(const half8*)(base + (size_t)node * DEMB);
  float acc[8];
#pragma unroll
  for (int j = 0; j < 8; ++j) acc[j] = (float)sv[j];
  float s = WITHU ? a_in[node] : 0.f;
  int e = off[node], end = off[node + 1];
  // 8-deep
  for (; e + 8 <= end; e += 8) {
    int i0 = csr[e], i1 = csr[e + 1], i2 = csr[e + 2], i3 = csr[e + 3];
    int i4 = csr[e + 4], i5 = csr[e + 5], i6 = csr[e + 6], i7 = csr[e + 7];
    half8 r0 = *(const half8*)(base + (size_t)i0 * DEMB);
    half8 r1 = *(const half8*)(base + (size_t)i1 * DEMB);
    half8 r2 = *(const half8*)(base + (size_t)i2 * DEMB);
    half8 r3 = *(const half8*)(base + (size_t)i3 * DEMB);
    half8 r4 = *(const half8*)(base + (size_t)i4 * DEMB);
    half8 r5 = *(const half8*)(base + (size_t)i5 * DEMB);
    half8 r6 = *(const half8*)(base + (size_t)i6 * DEMB);
    half8 r7 = *(const half8*)(base + (size_t)i7 * DEMB);
    if (WITHU)
      s += a_in[i0] + a_in[i1] + a_in[i2] + a_in[i3] +
           a_in[i4] + a_in[i5] + a_in[i6] + a_in[i7];
#pragma unroll
    for (int j = 0; j < 8; ++j)
      acc[j] += ((float)r0[j] + (float)r1[j]) + ((float)r2[j] + (float)r3[j]) +
                ((float)r4[j] + (float)r5[j]) + ((float)r6[j] + (float)r7[j]);
  }
  // 4-deep
  for (; e + 4 <= end; e += 4) {
    int i0 = csr[e], i1 = csr[e + 1], i2 = csr[e + 2], i3 = csr[e + 3];
    half8 r0 = *(const half8*)(base + (size_t)i0 * DEMB);
    half8 r1 = *(const half8*)(base + (size_t)i1 * DEMB);
    half8 r2 = *(const half8*)(base + (size_t)i2 * DEMB);
    half8 r3 = *(const half8*)(base + (size_t)i3 * DEMB);
    if (WITHU) s += a_in[i0] + a_in[i1] + a_in[i2] + a_in[i3];
#pragma unroll
    for (int j = 0; j < 8; ++j)
      acc[j] += ((float)r0[j] + (float)r1[j]) + ((float)r2[j] + (float)r3[j]);
  }
  // tail (<=3)
  if (e < end) {
    int em = end - 1;
    int i0 = csr[e];
    int i1 = csr[min(e + 1, em)];
    int i2 = csr[min(e + 2, em)];
    float w1 = (e + 1 < end) ? 1.f : 0.f;
    float w2 = (e + 2 < end) ? 1.f : 0.f;
    half8 r0 = *(const half8*)(base + (size_t)i0 * DEMB);
    half8 r1 = *(const half8*)(base + (size_t)i1 * DEMB);
    half8 r2 = *(const half8*)(base + (size_t)i2 * DEMB);
    if (WITHU) s += a_in[i0] + w1 * a_in[i1] + w2 * a_in[i2];
#pragma unroll
    for (int j = 0; j < 8; ++j)
      acc[j] += (float)r0[j] + w1 * (float)r1[j] + w2 * (float)r2[j];
  }
  float sc = scale[node];
  half8 o;
#pragma unroll
  for (int j = 0; j < 8; ++j) o[j] = (_Float16)(acc[j] * sc);
  *(half8*)(vout + (size_t)node * DEMB + 8 * l16) = o;
  if (WITHU && l16 == 0) {
    float dv = dinv[node];
    float u = dv * s;
    u_out[node] = u;
    a_out[node] = dv * u;
  }
}

// ---------- final MFMA GEMM: out[r][c] = sum_k y[r][k]*Rh[c][k]
//            + u3[r]*cb[c] + u2[r]*cb[128+c] + u1[r]*cb[256+c] + b3[c]
__launch_bounds__(256)
__global__ void kgemm16(const _Float16* __restrict__ y, const _Float16* __restrict__ Rh,
                        const float* __restrict__ u1, const float* __restrict__ u2,
                        const float* __restrict__ u3, const float* __restrict__ cb,
                        const float* __restrict__ b3, float* __restrict__ out, int n) {
  int t = threadIdx.x;
  int wv = t >> 6, lane = t & 63;
  int l16 = lane & 15, g = lane >> 4;
  int row0 = blockIdx.x * 128 + wv * 32;
  f32x4 acc[2][8];
#pragma unroll
  for (int w = 0; w < 2; ++w)
#pragma unroll
    for (int n8 = 0; n8 < 8; ++n8) acc[w][n8] = (f32x4){0.f, 0.f, 0.f, 0.f};

#pragma unroll
  for (int k0 = 0; k0 < 128; k0 += 32) {
    half8 a0 = *(const half8*)(y + (size_t)(row0 + l16) * DEMB + k0 + g * 8);
    half8 a1 = *(const half8*)(y + (size_t)(row0 + 16 + l16) * DEMB + k0 + g * 8);
#pragma unroll
    for (int n8 = 0; n8 < 8; ++n8) {
      half8 b = *(const half8*)(Rh + (size_t)(n8 * 16 + l16) * DEMB + k0 + g * 8);
      acc[0][n8] = __builtin_amdgcn_mfma_f32_16x16x32_f16(a0, b, acc[0][n8], 0, 0, 0);
      acc[1][n8] = __builtin_amdgcn_mfma_f32_16x16x32_f16(a1, b, acc[1][n8], 0, 0, 0);
    }
  }
#pragma unroll
  for (int n8 = 0; n8 < 8; ++n8) {
    int col = n8 * 16 + l16;
    float cA = cb[col], cB = cb[128 + col], cC = cb[256 + col], bb = b3[col];
#pragma unroll
    for (int w = 0; w < 2; ++w)
#pragma unroll
      for (int r = 0; r < 4; ++r) {
        int row = row0 + w * 16 + g * 4 + r;
        if (row < n) {
          out[(size_t)row * DEMB + col] =
              acc[w][n8][r] + u3[row] * cA + u2[row] * cB + u1[row] * cC + bb;
        }
      }
  }
}

extern "C" void kernel_launch(void* const* d_in, const int* in_sizes, int n_in,
                              void* d_out, int out_size, void* d_ws, size_t ws_size,
                              hipStream_t stream) {
  const float* x0 = (const float*)d_in[0];
  const int* ei = (const int*)d_in[1];
  const float* lin = (const float*)d_in[2];
  const float* gcn = (const float*)d_in[3];
  const float* gb = (const float*)d_in[4];
  float* out = (float*)d_out;

  int N = in_sizes[0] / DEMB;
  int E = in_sizes[1] / 2;
  int L = in_sizes[2] / (DEMB * DEMB);  // = 4
  int NP = (N + 127) & ~127;

  char* w = (char*)d_ws;
  auto carve = [&](size_t bytes) {
    char* p = w;
    w += (bytes + 255) & ~(size_t)255;
    return p;
  };
  float* Ms    = (float*)carve((size_t)L * DEMB * DEMB * 4);
  float* A1    = (float*)carve((size_t)DEMB * DEMB * 4);
  float* B1    = (float*)carve((size_t)DEMB * DEMB * 4);
  _Float16* Rh = (_Float16*)carve((size_t)DEMB * DEMB * 2);
  float* v0    = (float*)carve((size_t)DEMB * 4);
  float* cb    = (float*)carve((size_t)3 * DEMB * 4);
  float* dinv  = (float*)carve((size_t)N * 4);
  float* dnv2  = (float*)carve((size_t)N * 4);
  int* deg     = (int*)carve((size_t)N * 4);
  int* off     = (int*)carve((size_t)(N + 1) * 4);
  int* cur     = (int*)carve((size_t)N * 4);
  int* bsum    = (int*)carve(256 * 4);
  int* boff    = (int*)carve(256 * 4);
  int* csr     = (int*)carve((size_t)E * 4);
  float* u1    = (float*)carve((size_t)N * 4);
  float* u2    = (float*)carve((size_t)N * 4);
  float* u3    = (float*)carve((size_t)N * 4);
  float* a1    = (float*)carve((size_t)N * 4);
  float* a2    = (float*)carve((size_t)N * 4);
  float* a3    = (float*)carve((size_t)N * 4);
  _Float16* ha = (_Float16*)carve((size_t)NP * DEMB * 2);
  _Float16* hb = (_Float16*)carve((size_t)NP * DEMB * 2);
  (void)ws_size; (void)n_in; (void)out_size;

  int nbN = (N + 255) / 256;
  int nbE = (E + 255) / 256;
  int nbA = (N * 16 + 255) / 256;  // agg: 16 threads per node

  // zero degree counters
  hipMemsetAsync(deg, 0, (size_t)N * 4, stream);

  // weight/bias precompute (3 launches)
  kwc<<<L * DEMB, DEMB, 0, stream>>>(gcn, lin, Ms);
  kst2<<<258, DEMB, 0, stream>>>(Ms, gb, A1, B1, v0, cb);
  kst3<<<130, DEMB, 0, stream>>>(A1, B1, v0, gb, Rh, cb);

  // graph prep (5 launches)
  kdeg<<<nbE, 256, 0, stream>>>(ei, deg, E);
  kscan1<<<nbN, 256, 0, stream>>>(deg, off, bsum, dinv, dnv2, N);
  kscan2<<<1, 256, 0, stream>>>(bsum, boff, nbN, off, N, E);
  kscan3<<<nbN, 256, 0, stream>>>(off, boff, cur, N);
  kfill<<<nbE, 256, 0, stream>>>(ei, cur, csr, E);

  // prescale + 4 chained fp16 aggregations with fused u-chain
  kpre<<<(N * 32 + 255) / 256, 256, 0, stream>>>(x0, dinv, ha, N);
  kagg16<1><<<nbA, 256, 0, stream>>>(ha, csr, off, dnv2, dinv, dinv, u1, a1, hb, N);
  kagg16<1><<<nbA, 256, 0, stream>>>(hb, csr, off, dnv2, dinv, a1, u2, a2, ha, N);
  kagg16<1><<<nbA, 256, 0, stream>>>(ha, csr, off, dnv2, dinv, a2, u3, a3, hb, N);
  kagg16<0><<<nbA, 256, 0, stream>>>(hb, csr, off, dinv, dinv, nullptr, nullptr, nullptr, ha, N);

  // final fp16-MFMA GEMM with rank-1 bias terms -> fp32 out
  kgemm16<<<(N + 127) / 128, 256, 0, stream>>>(ha, Rh, u1, u2, u3, cb, gb + 3 * DEMB, out, N);
}

// Round 10
// 220.042 us; speedup vs baseline: 1.2539x; 1.0604x over previous
//
#include <hip/hip_runtime.h>

#define DEMB 128
#define EB 8192  // edges per block in khist/kscatter

typedef __attribute__((ext_vector_type(8))) _Float16 half8;
typedef __attribute__((ext_vector_type(4))) _Float16 half4;
typedef __attribute__((ext_vector_type(4))) float f32x4;

// ---------- Ms[l] = gcn_l @ lin_l (row-major), grid L*128, block 128
__global__ void kwc(const float* __restrict__ gcn, const float* __restrict__ lin,
                    float* __restrict__ Ms) {
  __shared__ float sa[128];
  int l = blockIdx.x >> 7, i = blockIdx.x & 127, j = threadIdx.x;
  sa[j] = gcn[((size_t)l * 128 + i) * 128 + j];
  __syncthreads();
  float acc = 0.f;
#pragma unroll 8
  for (int k = 0; k < 128; ++k) acc += sa[k] * lin[((size_t)l * 128 + k) * 128 + j];
  Ms[((size_t)l * 128 + i) * 128 + j] = acc;
}

// ---------- stage 2: A1 = M1@M0, B1 = M3@M2, v0 = M1@b0, cC = M3@b2
__global__ void kst2(const float* __restrict__ Ms, const float* __restrict__ gb,
                     float* __restrict__ A1, float* __restrict__ B1,
                     float* __restrict__ v0, float* __restrict__ cb) {
  const float* M0 = Ms;
  const float* M1 = Ms + 16384;
  const float* M2 = Ms + 2 * 16384;
  const float* M3 = Ms + 3 * 16384;
  __shared__ float sa[128];
  int b = blockIdx.x, j = threadIdx.x;
  if (b < 128) {
    sa[j] = M1[b * 128 + j];
    __syncthreads();
    float acc = 0.f;
#pragma unroll 8
    for (int k = 0; k < 128; ++k) acc += sa[k] * M0[k * 128 + j];
    A1[b * 128 + j] = acc;
  } else if (b < 256) {
    int i = b - 128;
    sa[j] = M3[i * 128 + j];
    __syncthreads();
    float acc = 0.f;
#pragma unroll 8
    for (int k = 0; k < 128; ++k) acc += sa[k] * M2[k * 128 + j];
    B1[i * 128 + j] = acc;
  } else if (b == 256) {
    sa[j] = gb[j];
    __syncthreads();
    float acc = 0.f;
#pragma unroll 8
    for (int k = 0; k < 128; ++k) acc += M1[j * 128 + k] * sa[k];
    v0[j] = acc;
  } else {
    sa[j] = gb[2 * 128 + j];
    __syncthreads();
    float acc = 0.f;
#pragma unroll 8
    for (int k = 0; k < 128; ++k) acc += M3[j * 128 + k] * sa[k];
    cb[256 + j] = acc;  // cC
  }
}

// ---------- stage 3: Rh = fp16(B1@A1) row-major [c][k], cA = B1@v0, cB = B1@b1
__global__ void kst3(const float* __restrict__ A1, const float* __restrict__ B1,
                     const float* __restrict__ v0, const float* __restrict__ gb,
                     _Float16* __restrict__ Rh, float* __restrict__ cb) {
  __shared__ float sa[128];
  int b = blockIdx.x, j = threadIdx.x;
  if (b < 128) {
    sa[j] = B1[b * 128 + j];
    __syncthreads();
    float acc = 0.f;
#pragma unroll 8
    for (int k = 0; k < 128; ++k) acc += sa[k] * A1[k * 128 + j];
    Rh[b * 128 + j] = (_Float16)acc;
  } else if (b == 128) {
    sa[j] = v0[j];
    __syncthreads();
    float acc = 0.f;
#pragma unroll 8
    for (int k = 0; k < 128; ++k) acc += B1[j * 128 + k] * sa[k];
    cb[j] = acc;  // cA
  } else {
    sa[j] = gb[128 + j];
    __syncthreads();
    float acc = 0.f;
#pragma unroll 8
    for (int k = 0; k < 128; ++k) acc += B1[j * 128 + k] * sa[k];
    cb[128 + j] = acc;  // cB
  }
}

// ---------- binned CSR build ----------
// bins = dst >> 8 (256 nodes each). khist: per-block LDS histogram -> histG[bin][block].
__global__ void khist(const int* __restrict__ ei, int* __restrict__ histG,
                      int etot, int nbB) {
  __shared__ int lh[256];
  int t = threadIdx.x;
  lh[t] = 0;
  __syncthreads();
#pragma unroll 4
  for (int j = 0; j < EB / 256; ++j) {
    int i = blockIdx.x * EB + j * 256 + t;  // coalesced rounds
    if (i < etot) atomicAdd(&lh[ei[etot + i] >> 8], 1);
  }
  __syncthreads();
  histG[t * nbB + blockIdx.x] = lh[t];
}

// kbase (1 block): per-bin totals -> exclusive bin scan -> binOff; rewrite histG to
// per-(bin,block) global bases.
__global__ void kbase(int* __restrict__ histG, int* __restrict__ binOff,
                      int nbB, int etot) {
  __shared__ int s[256];
  int t = threadIdx.x;
  int* row = histG + t * nbB;
  int tot = 0;
#pragma unroll 4
  for (int b = 0; b < nbB; ++b) tot += row[b];
  s[t] = tot;
  __syncthreads();
  for (int o = 1; o < 256; o <<= 1) {
    int v = (t >= o) ? s[t - o] : 0;
    __syncthreads();
    s[t] += v;
    __syncthreads();
  }
  int bstart = s[t] - tot;
  binOff[t] = bstart;
  if (t == 255) binOff[256] = etot;
  int run = bstart;
  for (int b = 0; b < nbB; ++b) {
    int v = row[b];
    row[b] = run;
    run += v;
  }
}

// kscatter: scatter (src,dst) pairs into bin-grouped runs (block-contiguous).
__global__ void kscatter(const int* __restrict__ ei, const int* __restrict__ histG,
                         int2* __restrict__ pr, int etot, int nbB) {
  __shared__ int cur[256];
  int t = threadIdx.x;
  cur[t] = histG[t * nbB + blockIdx.x];
  __syncthreads();
#pragma unroll 4
  for (int j = 0; j < EB / 256; ++j) {
    int i = blockIdx.x * EB + j * 256 + t;
    if (i < etot) {
      int src = ei[i], dst = ei[etot + i];
      int p = atomicAdd(&cur[dst >> 8], 1);
      pr[p] = make_int2(src, dst);
    }
  }
}

// kdeg2: one block per bin; LDS degree counts, zero global atomics, coalesced write.
__global__ void kdeg2(const int2* __restrict__ pr, const int* __restrict__ binOff,
                      int* __restrict__ deg, int n) {
  __shared__ int dl[256];
  int t = threadIdx.x, b = blockIdx.x;
  dl[t] = 0;
  __syncthreads();
  int s1 = binOff[b + 1];
  for (int p = binOff[b] + t; p < s1; p += 256)
    atomicAdd(&dl[pr[p].y & 255], 1);
  __syncthreads();
  int node = (b << 8) + t;
  if (node < n) deg[node] = dl[t];
}

// scan step 1 (+ dinv/dinv2, self-loop +1 folded)
__global__ void kscan1(const int* __restrict__ deg, int* __restrict__ off,
                       int* __restrict__ bsum, float* __restrict__ dinv,
                       float* __restrict__ dinv2, int n) {
  __shared__ int s[256];
  int t = threadIdx.x, i = blockIdx.x * 256 + t;
  int c = 0;
  if (i < n) {
    c = deg[i];
    float dv = rsqrtf((float)(c + 1));
    dinv[i] = dv;
    dinv2[i] = dv * dv;
  }
  s[t] = c;
  __syncthreads();
  for (int o = 1; o < 256; o <<= 1) {
    int v = (t >= o) ? s[t - o] : 0;
    __syncthreads();
    s[t] += v;
    __syncthreads();
  }
  if (i < n) off[i] = s[t] - c;
  if (t == 255) bsum[blockIdx.x] = s[t];
}

__global__ void kscan2(const int* __restrict__ bsum, int* __restrict__ boff,
                       int nb, int* __restrict__ off, int n, int etot) {
  __shared__ int s[256];
  int t = threadIdx.x;
  int c = (t < nb) ? bsum[t] : 0;
  s[t] = c;
  __syncthreads();
  for (int o = 1; o < 256; o <<= 1) {
    int v = (t >= o) ? s[t - o] : 0;
    __syncthreads();
    s[t] += v;
    __syncthreads();
  }
  if (t < nb) boff[t] = s[t] - c;
  if (t == 0) off[n] = etot;
}

__global__ void kscan3(int* __restrict__ off, const int* __restrict__ boff, int n) {
  int i = blockIdx.x * 256 + threadIdx.x;
  if (i < n) off[i] += boff[i >> 8];
}

// kfill2: one block per bin; LDS cursors seeded from off; csr writes stay in the
// bin's ~12KB region (one block -> one XCD, no line ping-pong).
__global__ void kfill2(const int2* __restrict__ pr, const int* __restrict__ binOff,
                       const int* __restrict__ off, int* __restrict__ csr, int n) {
  __shared__ int cur[256];
  int t = threadIdx.x, b = blockIdx.x;
  int node = (b << 8) + t;
  cur[t] = (node < n) ? off[node] : 0;
  __syncthreads();
  int s1 = binOff[b + 1];
  for (int p = binOff[b] + t; p < s1; p += 256) {
    int2 e = pr[p];
    int pos = atomicAdd(&cur[e.y & 255], 1);
    csr[pos] = e.x;
  }
}

// ---------- prescale: xh[i][c] = fp16(x[i][c] * dinv[i])
__global__ void kpre(const float* __restrict__ x, const float* __restrict__ dinv,
                     _Float16* __restrict__ xh, int n) {
  int gid = blockIdx.x * 256 + threadIdx.x;
  if (gid >= n * 32) return;
  int r = gid >> 5, c = (gid & 31) * 4;
  float d = dinv[r];
  float4 v = *(const float4*)(x + (size_t)r * DEMB + c);
  half4 o = {(_Float16)(v.x * d), (_Float16)(v.y * d), (_Float16)(v.z * d), (_Float16)(v.w * d)};
  *(half4*)(xh + (size_t)r * DEMB + c) = o;
}

// ---------- fp16 aggregation: quarter-wave (16 lanes) per node, 8/4/tail ladder (R4).
// vout[i] = fp16( scale[i] * (vin[i] + sum_src vin[src]) )
// WITHU: also u = dinv[i]*(a_in[i] + sum_src a_in[src]); u_out[i]=u; a_out[i]=dinv[i]*u
template <int WITHU>
__launch_bounds__(256)
__global__ void kagg16(const _Float16* __restrict__ vin, const int* __restrict__ csr,
                       const int* __restrict__ off, const float* __restrict__ scale,
                       const float* __restrict__ dinv, const float* __restrict__ a_in,
                       float* __restrict__ u_out, float* __restrict__ a_out,
                       _Float16* __restrict__ vout, int n) {
  int node = (int)((blockIdx.x * 256u + threadIdx.x) >> 4);
  if (node >= n) return;
  int l16 = threadIdx.x & 15;
  const _Float16* base = vin + 8 * l16;
  half8 sv = *(const half8*)(base + (size_t)node * DEMB);
  float acc[8];
#pragma unroll
  for (int j = 0; j < 8; ++j) acc[j] = (float)sv[j];
  float s = WITHU ? a_in[node] : 0.f;
  int e = off[node], end = off[node + 1];
  // 8-deep
  for (; e + 8 <= end; e += 8) {
    int i0 = csr[e], i1 = csr[e + 1], i2 = csr[e + 2], i3 = csr[e + 3];
    int i4 = csr[e + 4], i5 = csr[e + 5], i6 = csr[e + 6], i7 = csr[e + 7];
    half8 r0 = *(const half8*)(base + (size_t)i0 * DEMB);
    half8 r1 = *(const half8*)(base + (size_t)i1 * DEMB);
    half8 r2 = *(const half8*)(base + (size_t)i2 * DEMB);
    half8 r3 = *(const half8*)(base + (size_t)i3 * DEMB);
    half8 r4 = *(const half8*)(base + (size_t)i4 * DEMB);
    half8 r5 = *(const half8*)(base + (size_t)i5 * DEMB);
    half8 r6 = *(const half8*)(base + (size_t)i6 * DEMB);
    half8 r7 = *(const half8*)(base + (size_t)i7 * DEMB);
    if (WITHU)
      s += a_in[i0] + a_in[i1] + a_in[i2] + a_in[i3] +
           a_in[i4] + a_in[i5] + a_in[i6] + a_in[i7];
#pragma unroll
    for (int j = 0; j < 8; ++j)
      acc[j] += ((float)r0[j] + (float)r1[j]) + ((float)r2[j] + (float)r3[j]) +
                ((float)r4[j] + (float)r5[j]) + ((float)r6[j] + (float)r7[j]);
  }
  // 4-deep
  for (; e + 4 <= end; e += 4) {
    int i0 = csr[e], i1 = csr[e + 1], i2 = csr[e + 2], i3 = csr[e + 3];
    half8 r0 = *(const half8*)(base + (size_t)i0 * DEMB);
    half8 r1 = *(const half8*)(base + (size_t)i1 * DEMB);
    half8 r2 = *(const half8*)(base + (size_t)i2 * DEMB);
    half8 r3 = *(const half8*)(base + (size_t)i3 * DEMB);
    if (WITHU) s += a_in[i0] + a_in[i1] + a_in[i2] + a_in[i3];
#pragma unroll
    for (int j = 0; j < 8; ++j)
      acc[j] += ((float)r0[j] + (float)r1[j]) + ((float)r2[j] + (float)r3[j]);
  }
  // tail (<=3)
  if (e < end) {
    int em = end - 1;
    int i0 = csr[e];
    int i1 = csr[min(e + 1, em)];
    int i2 = csr[min(e + 2, em)];
    float w1 = (e + 1 < end) ? 1.f : 0.f;
    float w2 = (e + 2 < end) ? 1.f : 0.f;
    half8 r0 = *(const half8*)(base + (size_t)i0 * DEMB);
    half8 r1 = *(const half8*)(base + (size_t)i1 * DEMB);
    half8 r2 = *(const half8*)(base + (size_t)i2 * DEMB);
    if (WITHU) s += a_in[i0] + w1 * a_in[i1] + w2 * a_in[i2];
#pragma unroll
    for (int j = 0; j < 8; ++j)
      acc[j] += (float)r0[j] + w1 * (float)r1[j] + w2 * (float)r2[j];
  }
  float sc = scale[node];
  half8 o;
#pragma unroll
  for (int j = 0; j < 8; ++j) o[j] = (_Float16)(acc[j] * sc);
  *(half8*)(vout + (size_t)node * DEMB + 8 * l16) = o;
  if (WITHU && l16 == 0) {
    float dv = dinv[node];
    float u = dv * s;
    u_out[node] = u;
    a_out[node] = dv * u;
  }
}

// ---------- final MFMA GEMM: out[r][c] = sum_k y[r][k]*Rh[c][k]
//            + u3[r]*cb[c] + u2[r]*cb[128+c] + u1[r]*cb[256+c] + b3[c]
__launch_bounds__(256)
__global__ void kgemm16(const _Float16* __restrict__ y, const _Float16* __restrict__ Rh,
                        const float* __restrict__ u1, const float* __restrict__ u2,
                        const float* __restrict__ u3, const float* __restrict__ cb,
                        const float* __restrict__ b3, float* __restrict__ out, int n) {
  int t = threadIdx.x;
  int wv = t >> 6, lane = t & 63;
  int l16 = lane & 15, g = lane >> 4;
  int row0 = blockIdx.x * 128 + wv * 32;
  f32x4 acc[2][8];
#pragma unroll
  for (int w = 0; w < 2; ++w)
#pragma unroll
    for (int n8 = 0; n8 < 8; ++n8) acc[w][n8] = (f32x4){0.f, 0.f, 0.f, 0.f};

#pragma unroll
  for (int k0 = 0; k0 < 128; k0 += 32) {
    half8 a0 = *(const half8*)(y + (size_t)(row0 + l16) * DEMB + k0 + g * 8);
    half8 a1 = *(const half8*)(y + (size_t)(row0 + 16 + l16) * DEMB + k0 + g * 8);
#pragma unroll
    for (int n8 = 0; n8 < 8; ++n8) {
      half8 b = *(const half8*)(Rh + (size_t)(n8 * 16 + l16) * DEMB + k0 + g * 8);
      acc[0][n8] = __builtin_amdgcn_mfma_f32_16x16x32_f16(a0, b, acc[0][n8], 0, 0, 0);
      acc[1][n8] = __builtin_amdgcn_mfma_f32_16x16x32_f16(a1, b, acc[1][n8], 0, 0, 0);
    }
  }
#pragma unroll
  for (int n8 = 0; n8 < 8; ++n8) {
    int col = n8 * 16 + l16;
    float cA = cb[col], cB = cb[128 + col], cC = cb[256 + col], bb = b3[col];
#pragma unroll
    for (int w = 0; w < 2; ++w)
#pragma unroll
      for (int r = 0; r < 4; ++r) {
        int row = row0 + w * 16 + g * 4 + r;
        if (row < n) {
          out[(size_t)row * DEMB + col] =
              acc[w][n8][r] + u3[row] * cA + u2[row] * cB + u1[row] * cC + bb;
        }
      }
  }
}

extern "C" void kernel_launch(void* const* d_in, const int* in_sizes, int n_in,
                              void* d_out, int out_size, void* d_ws, size_t ws_size,
                              hipStream_t stream) {
  const float* x0 = (const float*)d_in[0];
  const int* ei = (const int*)d_in[1];
  const float* lin = (const float*)d_in[2];
  const float* gcn = (const float*)d_in[3];
  const float* gb = (const float*)d_in[4];
  float* out = (float*)d_out;

  int N = in_sizes[0] / DEMB;
  int E = in_sizes[1] / 2;
  int L = in_sizes[2] / (DEMB * DEMB);  // = 4
  int NP = (N + 127) & ~127;
  int NBINS = (N + 255) >> 8;           // 196
  int nbB = (E + EB - 1) / EB;          // 74

  char* w = (char*)d_ws;
  auto carve = [&](size_t bytes) {
    char* p = w;
    w += (bytes + 255) & ~(size_t)255;
    return p;
  };
  float* Ms    = (float*)carve((size_t)L * DEMB * DEMB * 4);
  float* A1    = (float*)carve((size_t)DEMB * DEMB * 4);
  float* B1    = (float*)carve((size_t)DEMB * DEMB * 4);
  _Float16* Rh = (_Float16*)carve((size_t)DEMB * DEMB * 2);
  float* v0    = (float*)carve((size_t)DEMB * 4);
  float* cb    = (float*)carve((size_t)3 * DEMB * 4);
  float* dinv  = (float*)carve((size_t)N * 4);
  float* dnv2  = (float*)carve((size_t)N * 4);
  int* deg     = (int*)carve((size_t)N * 4);
  int* off     = (int*)carve((size_t)(N + 1) * 4);
  int* histG   = (int*)carve((size_t)256 * nbB * 4);
  int* binOff  = (int*)carve(257 * 4);
  int2* pr     = (int2*)carve((size_t)E * 8);
  int* bsum    = (int*)carve(256 * 4);
  int* boff    = (int*)carve(256 * 4);
  int* csr     = (int*)carve((size_t)E * 4);
  float* u1    = (float*)carve((size_t)N * 4);
  float* u2    = (float*)carve((size_t)N * 4);
  float* u3    = (float*)carve((size_t)N * 4);
  float* a1    = (float*)carve((size_t)N * 4);
  float* a2    = (float*)carve((size_t)N * 4);
  float* a3    = (float*)carve((size_t)N * 4);
  _Float16* ha = (_Float16*)carve((size_t)NP * DEMB * 2);
  _Float16* hb = (_Float16*)carve((size_t)NP * DEMB * 2);
  (void)ws_size; (void)n_in; (void)out_size;

  int nbN = (N + 255) / 256;

  // weight/bias precompute (3 launches)
  kwc<<<L * DEMB, DEMB, 0, stream>>>(gcn, lin, Ms);
  kst2<<<258, DEMB, 0, stream>>>(Ms, gb, A1, B1, v0, cb);
  kst3<<<130, DEMB, 0, stream>>>(A1, B1, v0, gb, Rh, cb);

  // binned CSR build (8 launches, no global atomics on hot lines)
  khist<<<nbB, 256, 0, stream>>>(ei, histG, E, nbB);
  kbase<<<1, 256, 0, stream>>>(histG, binOff, nbB, E);
  kscatter<<<nbB, 256, 0, stream>>>(ei, histG, pr, E, nbB);
  kdeg2<<<NBINS, 256, 0, stream>>>(pr, binOff, deg, N);
  kscan1<<<nbN, 256, 0, stream>>>(deg, off, bsum, dinv, dnv2, N);
  kscan2<<<1, 256, 0, stream>>>(bsum, boff, nbN, off, N, E);
  kscan3<<<nbN, 256, 0, stream>>>(off, boff, N);
  kfill2<<<NBINS, 256, 0, stream>>>(pr, binOff, off, csr, N);

  // prescale + 4 chained fp16 aggregations with fused u-chain
  kpre<<<(N * 32 + 255) / 256, 256, 0, stream>>>(x0, dinv, ha, N);
  int nbA = (N * 16 + 255) / 256;
  kagg16<1><<<nbA, 256, 0, stream>>>(ha, csr, off, dnv2, dinv, dinv, u1, a1, hb, N);
  kagg16<1><<<nbA, 256, 0, stream>>>(hb, csr, off, dnv2, dinv, a1, u2, a2, ha, N);
  kagg16<1><<<nbA, 256, 0, stream>>>(ha, csr, off, dnv2, dinv, a2, u3, a3, hb, N);
  kagg16<0><<<nbA, 256, 0, stream>>>(hb, csr, off, dinv, dinv, nullptr, nullptr, nullptr, ha, N);

  // final fp16-MFMA GEMM with rank-1 bias terms -> fp32 out
  kgemm16<<<(N + 127) / 128, 256, 0, stream>>>(ha, Rh, u1, u2, u3, cb, gb + 3 * DEMB, out, N);
}

// Round 11
// 217.936 us; speedup vs baseline: 1.2660x; 1.0097x over previous
//
#include <hip/hip_runtime.h>

#define DEMB 128
#define EB 8192  // edges per block in khist/kscatter

typedef __attribute__((ext_vector_type(8))) _Float16 half8;
typedef __attribute__((ext_vector_type(4))) _Float16 half4;
typedef __attribute__((ext_vector_type(4))) float f32x4;

// ---------- fused weight/bias chain (one launch, 130 blocks x 128 thr)
// blocks 0..127: row b of R = M3@M2@M1@M0 (Ml = gcn_l@lin_l) via vec-mat chain -> Rh fp16
// block 128:     cA = M3 M2 M1 b0  (mat-vec chain, right-to-left)
// block 129:     cB = M3 M2 b1 ; cC = M3 b2
__global__ void kweights(const float* __restrict__ gcn, const float* __restrict__ lin,
                         const float* __restrict__ gb, _Float16* __restrict__ Rh,
                         float* __restrict__ cb) {
  __shared__ float va[128], vb[128];
  int b = blockIdx.x, j = threadIdx.x;
  const float* G0 = gcn;
  const float* G1 = gcn + 16384;
  const float* G2 = gcn + 2 * 16384;
  const float* G3 = gcn + 3 * 16384;
  const float* L0 = lin;
  const float* L1 = lin + 16384;
  const float* L2 = lin + 2 * 16384;
  const float* L3 = lin + 3 * 16384;
  float* cur = va;
  float* nxt = vb;
  if (b < 128) {
    // v = row b of gcn3; then v = v@L3, @G2, @L2, @G1, @L1, @G0, @L0  (coalesced reads)
    const float* seq[7] = {L3, G2, L2, G1, L1, G0, L0};
    va[j] = G3[b * 128 + j];
    __syncthreads();
#pragma unroll
    for (int s = 0; s < 7; ++s) {
      const float* M = seq[s];
      float acc = 0.f;
#pragma unroll 8
      for (int k = 0; k < 128; ++k) acc += cur[k] * M[k * 128 + j];
      nxt[j] = acc;
      __syncthreads();
      float* t2 = cur; cur = nxt; nxt = t2;
    }
    Rh[b * 128 + j] = (_Float16)cur[j];
  } else if (b == 128) {
    // cA: v = b0; v = L1@v, G1@v, L2@v, G2@v, L3@v, G3@v
    const float* seq[6] = {L1, G1, L2, G2, L3, G3};
    va[j] = gb[j];
    __syncthreads();
#pragma unroll
    for (int s = 0; s < 6; ++s) {
      const float* M = seq[s];
      float acc = 0.f;
#pragma unroll 8
      for (int k = 0; k < 128; ++k) acc += M[j * 128 + k] * cur[k];
      nxt[j] = acc;
      __syncthreads();
      float* t2 = cur; cur = nxt; nxt = t2;
    }
    cb[j] = cur[j];
  } else {
    // cB: v = b1; v = L2@v, G2@v, L3@v, G3@v
    const float* seqB[4] = {L2, G2, L3, G3};
    va[j] = gb[128 + j];
    __syncthreads();
#pragma unroll
    for (int s = 0; s < 4; ++s) {
      const float* M = seqB[s];
      float acc = 0.f;
#pragma unroll 8
      for (int k = 0; k < 128; ++k) acc += M[j * 128 + k] * cur[k];
      nxt[j] = acc;
      __syncthreads();
      float* t2 = cur; cur = nxt; nxt = t2;
    }
    cb[128 + j] = cur[j];
    __syncthreads();
    // cC: v = b2; v = L3@v, G3@v
    cur[j] = gb[256 + j];
    __syncthreads();
    const float* seqC[2] = {L3, G3};
#pragma unroll
    for (int s = 0; s < 2; ++s) {
      const float* M = seqC[s];
      float acc = 0.f;
#pragma unroll 8
      for (int k = 0; k < 128; ++k) acc += M[j * 128 + k] * cur[k];
      nxt[j] = acc;
      __syncthreads();
      float* t2 = cur; cur = nxt; nxt = t2;
    }
    cb[256 + j] = cur[j];
  }
}

// ---------- binned CSR build ----------
// bins = dst >> 8 (256 nodes each). khist: per-block LDS histogram -> histG[bin][block].
__global__ void khist(const int* __restrict__ ei, int* __restrict__ histG,
                      int etot, int nbB) {
  __shared__ int lh[256];
  int t = threadIdx.x;
  lh[t] = 0;
  __syncthreads();
#pragma unroll 4
  for (int j = 0; j < EB / 256; ++j) {
    int i = blockIdx.x * EB + j * 256 + t;  // coalesced rounds
    if (i < etot) atomicAdd(&lh[ei[etot + i] >> 8], 1);
  }
  __syncthreads();
  histG[t * nbB + blockIdx.x] = lh[t];
}

// kbase (1 block): per-bin totals -> exclusive bin scan -> binOff; rewrite histG to
// per-(bin,block) global bases.
__global__ void kbase(int* __restrict__ histG, int* __restrict__ binOff,
                      int nbB, int etot) {
  __shared__ int s[256];
  int t = threadIdx.x;
  int* row = histG + t * nbB;
  int tot = 0;
#pragma unroll 4
  for (int b = 0; b < nbB; ++b) tot += row[b];
  s[t] = tot;
  __syncthreads();
  for (int o = 1; o < 256; o <<= 1) {
    int v = (t >= o) ? s[t - o] : 0;
    __syncthreads();
    s[t] += v;
    __syncthreads();
  }
  int bstart = s[t] - tot;
  binOff[t] = bstart;
  if (t == 255) binOff[256] = etot;
  int run = bstart;
#pragma unroll 4
  for (int b = 0; b < nbB; ++b) {
    int v = row[b];
    row[b] = run;
    run += v;
  }
}

// kscatter: scatter packed (src<<8 | dst&255) into bin-grouped runs.
__global__ void kscatter(const int* __restrict__ ei, const int* __restrict__ histG,
                         int* __restrict__ pr, int etot, int nbB) {
  __shared__ int cur[256];
  int t = threadIdx.x;
  cur[t] = histG[t * nbB + blockIdx.x];
  __syncthreads();
#pragma unroll 4
  for (int j = 0; j < EB / 256; ++j) {
    int i = blockIdx.x * EB + j * 256 + t;
    if (i < etot) {
      int src = ei[i], dst = ei[etot + i];
      int p = atomicAdd(&cur[dst >> 8], 1);
      pr[p] = (src << 8) | (dst & 255);
    }
  }
}

// kscan1 (fused degree count): block b = bin b; LDS degree histogram from pr,
// then edge-offset scan + dinv/dinv2 (self-loop +1 folded).
__global__ void kscan1(const int* __restrict__ pr, const int* __restrict__ binOff,
                       int* __restrict__ off, int* __restrict__ bsum,
                       float* __restrict__ dinv, float* __restrict__ dinv2, int n) {
  __shared__ int dl[256];
  __shared__ int s[256];
  int t = threadIdx.x, b = blockIdx.x;
  dl[t] = 0;
  __syncthreads();
  int s1 = binOff[b + 1];
  for (int p = binOff[b] + t; p < s1; p += 256)
    atomicAdd(&dl[pr[p] & 255], 1);
  __syncthreads();
  int i = b * 256 + t;
  int c = 0;
  if (i < n) {
    c = dl[t];
    float dv = rsqrtf((float)(c + 1));
    dinv[i] = dv;
    dinv2[i] = dv * dv;
  }
  s[t] = c;
  __syncthreads();
  for (int o = 1; o < 256; o <<= 1) {
    int v = (t >= o) ? s[t - o] : 0;
    __syncthreads();
    s[t] += v;
    __syncthreads();
  }
  if (i < n) off[i] = s[t] - c;
  if (t == 255) bsum[b] = s[t];
}

__global__ void kscan2(const int* __restrict__ bsum, int* __restrict__ boff,
                       int nb, int* __restrict__ off, int n, int etot) {
  __shared__ int s[256];
  int t = threadIdx.x;
  int c = (t < nb) ? bsum[t] : 0;
  s[t] = c;
  __syncthreads();
  for (int o = 1; o < 256; o <<= 1) {
    int v = (t >= o) ? s[t - o] : 0;
    __syncthreads();
    s[t] += v;
    __syncthreads();
  }
  if (t < nb) boff[t] = s[t] - c;
  if (t == 0) off[n] = etot;
}

// kfill2 (fused off-finalize): block b = bin b; off[node] += boff[b] (finalized),
// LDS cursors, csr writes confined to this bin's region.
__global__ void kfill2(const int* __restrict__ pr, const int* __restrict__ binOff,
                       const int* __restrict__ boff, int* __restrict__ off,
                       int* __restrict__ csr, int n) {
  __shared__ int cur[256];
  int t = threadIdx.x, b = blockIdx.x;
  int node = (b << 8) + t;
  int o = 0;
  if (node < n) {
    o = off[node] + boff[b];
    off[node] = o;
  }
  cur[t] = o;
  __syncthreads();
  int s1 = binOff[b + 1];
  for (int p = binOff[b] + t; p < s1; p += 256) {
    int v = pr[p];
    int pos = atomicAdd(&cur[v & 255], 1);
    csr[pos] = v >> 8;
  }
}

// ---------- prescale: xh[i][c] = fp16(x[i][c] * dinv[i])
__global__ void kpre(const float* __restrict__ x, const float* __restrict__ dinv,
                     _Float16* __restrict__ xh, int n) {
  int gid = blockIdx.x * 256 + threadIdx.x;
  if (gid >= n * 32) return;
  int r = gid >> 5, c = (gid & 31) * 4;
  float d = dinv[r];
  float4 v = *(const float4*)(x + (size_t)r * DEMB + c);
  half4 o = {(_Float16)(v.x * d), (_Float16)(v.y * d), (_Float16)(v.z * d), (_Float16)(v.w * d)};
  *(half4*)(xh + (size_t)r * DEMB + c) = o;
}

// ---------- fp16 aggregation: quarter-wave (16 lanes) per node, 8/4/tail ladder (R4).
// vout[i] = fp16( scale[i] * (vin[i] + sum_src vin[src]) )
// WITHU: also u = dinv[i]*(a_in[i] + sum_src a_in[src]); u_out[i]=u; a_out[i]=dinv[i]*u
template <int WITHU>
__launch_bounds__(256)
__global__ void kagg16(const _Float16* __restrict__ vin, const int* __restrict__ csr,
                       const int* __restrict__ off, const float* __restrict__ scale,
                       const float* __restrict__ dinv, const float* __restrict__ a_in,
                       float* __restrict__ u_out, float* __restrict__ a_out,
                       _Float16* __restrict__ vout, int n) {
  int node = (int)((blockIdx.x * 256u + threadIdx.x) >> 4);
  if (node >= n) return;
  int l16 = threadIdx.x & 15;
  const _Float16* base = vin + 8 * l16;
  half8 sv = *(const half8*)(base + (size_t)node * DEMB);
  float acc[8];
#pragma unroll
  for (int j = 0; j < 8; ++j) acc[j] = (float)sv[j];
  float s = WITHU ? a_in[node] : 0.f;
  int e = off[node], end = off[node + 1];
  // 8-deep
  for (; e + 8 <= end; e += 8) {
    int i0 = csr[e], i1 = csr[e + 1], i2 = csr[e + 2], i3 = csr[e + 3];
    int i4 = csr[e + 4], i5 = csr[e + 5], i6 = csr[e + 6], i7 = csr[e + 7];
    half8 r0 = *(const half8*)(base + (size_t)i0 * DEMB);
    half8 r1 = *(const half8*)(base + (size_t)i1 * DEMB);
    half8 r2 = *(const half8*)(base + (size_t)i2 * DEMB);
    half8 r3 = *(const half8*)(base + (size_t)i3 * DEMB);
    half8 r4 = *(const half8*)(base + (size_t)i4 * DEMB);
    half8 r5 = *(const half8*)(base + (size_t)i5 * DEMB);
    half8 r6 = *(const half8*)(base + (size_t)i6 * DEMB);
    half8 r7 = *(const half8*)(base + (size_t)i7 * DEMB);
    if (WITHU)
      s += a_in[i0] + a_in[i1] + a_in[i2] + a_in[i3] +
           a_in[i4] + a_in[i5] + a_in[i6] + a_in[i7];
#pragma unroll
    for (int j = 0; j < 8; ++j)
      acc[j] += ((float)r0[j] + (float)r1[j]) + ((float)r2[j] + (float)r3[j]) +
                ((float)r4[j] + (float)r5[j]) + ((float)r6[j] + (float)r7[j]);
  }
  // 4-deep
  for (; e + 4 <= end; e += 4) {
    int i0 = csr[e], i1 = csr[e + 1], i2 = csr[e + 2], i3 = csr[e + 3];
    half8 r0 = *(const half8*)(base + (size_t)i0 * DEMB);
    half8 r1 = *(const half8*)(base + (size_t)i1 * DEMB);
    half8 r2 = *(const half8*)(base + (size_t)i2 * DEMB);
    half8 r3 = *(const half8*)(base + (size_t)i3 * DEMB);
    if (WITHU) s += a_in[i0] + a_in[i1] + a_in[i2] + a_in[i3];
#pragma unroll
    for (int j = 0; j < 8; ++j)
      acc[j] += ((float)r0[j] + (float)r1[j]) + ((float)r2[j] + (float)r3[j]);
  }
  // tail (<=3)
  if (e < end) {
    int em = end - 1;
    int i0 = csr[e];
    int i1 = csr[min(e + 1, em)];
    int i2 = csr[min(e + 2, em)];
    float w1 = (e + 1 < end) ? 1.f : 0.f;
    float w2 = (e + 2 < end) ? 1.f : 0.f;
    half8 r0 = *(const half8*)(base + (size_t)i0 * DEMB);
    half8 r1 = *(const half8*)(base + (size_t)i1 * DEMB);
    half8 r2 = *(const half8*)(base + (size_t)i2 * DEMB);
    if (WITHU) s += a_in[i0] + w1 * a_in[i1] + w2 * a_in[i2];
#pragma unroll
    for (int j = 0; j < 8; ++j)
      acc[j] += (float)r0[j] + w1 * (float)r1[j] + w2 * (float)r2[j];
  }
  float sc = scale[node];
  half8 o;
#pragma unroll
  for (int j = 0; j < 8; ++j) o[j] = (_Float16)(acc[j] * sc);
  *(half8*)(vout + (size_t)node * DEMB + 8 * l16) = o;
  if (WITHU && l16 == 0) {
    float dv = dinv[node];
    float u = dv * s;
    u_out[node] = u;
    a_out[node] = dv * u;
  }
}

// ---------- final MFMA GEMM: out[r][c] = sum_k y[r][k]*Rh[c][k]
//            + u3[r]*cb[c] + u2[r]*cb[128+c] + u1[r]*cb[256+c] + b3[c]
__launch_bounds__(256)
__global__ void kgemm16(const _Float16* __restrict__ y, const _Float16* __restrict__ Rh,
                        const float* __restrict__ u1, const float* __restrict__ u2,
                        const float* __restrict__ u3, const float* __restrict__ cb,
                        const float* __restrict__ b3, float* __restrict__ out, int n) {
  int t = threadIdx.x;
  int wv = t >> 6, lane = t & 63;
  int l16 = lane & 15, g = lane >> 4;
  int row0 = blockIdx.x * 128 + wv * 32;
  f32x4 acc[2][8];
#pragma unroll
  for (int w = 0; w < 2; ++w)
#pragma unroll
    for (int n8 = 0; n8 < 8; ++n8) acc[w][n8] = (f32x4){0.f, 0.f, 0.f, 0.f};

#pragma unroll
  for (int k0 = 0; k0 < 128; k0 += 32) {
    half8 a0 = *(const half8*)(y + (size_t)(row0 + l16) * DEMB + k0 + g * 8);
    half8 a1 = *(const half8*)(y + (size_t)(row0 + 16 + l16) * DEMB + k0 + g * 8);
#pragma unroll
    for (int n8 = 0; n8 < 8; ++n8) {
      half8 b = *(const half8*)(Rh + (size_t)(n8 * 16 + l16) * DEMB + k0 + g * 8);
      acc[0][n8] = __builtin_amdgcn_mfma_f32_16x16x32_f16(a0, b, acc[0][n8], 0, 0, 0);
      acc[1][n8] = __builtin_amdgcn_mfma_f32_16x16x32_f16(a1, b, acc[1][n8], 0, 0, 0);
    }
  }
#pragma unroll
  for (int n8 = 0; n8 < 8; ++n8) {
    int col = n8 * 16 + l16;
    float cA = cb[col], cB = cb[128 + col], cC = cb[256 + col], bb = b3[col];
#pragma unroll
    for (int w = 0; w < 2; ++w)
#pragma unroll
      for (int r = 0; r < 4; ++r) {
        int row = row0 + w * 16 + g * 4 + r;
        if (row < n) {
          out[(size_t)row * DEMB + col] =
              acc[w][n8][r] + u3[row] * cA + u2[row] * cB + u1[row] * cC + bb;
        }
      }
  }
}

extern "C" void kernel_launch(void* const* d_in, const int* in_sizes, int n_in,
                              void* d_out, int out_size, void* d_ws, size_t ws_size,
                              hipStream_t stream) {
  const float* x0 = (const float*)d_in[0];
  const int* ei = (const int*)d_in[1];
  const float* lin = (const float*)d_in[2];
  const float* gcn = (const float*)d_in[3];
  const float* gb = (const float*)d_in[4];
  float* out = (float*)d_out;

  int N = in_sizes[0] / DEMB;
  int E = in_sizes[1] / 2;
  int NP = (N + 127) & ~127;
  int NBINS = (N + 255) >> 8;           // 196
  int nbB = (E + EB - 1) / EB;          // 74

  char* w = (char*)d_ws;
  auto carve = [&](size_t bytes) {
    char* p = w;
    w += (bytes + 255) & ~(size_t)255;
    return p;
  };
  _Float16* Rh = (_Float16*)carve((size_t)DEMB * DEMB * 2);
  float* cb    = (float*)carve((size_t)3 * DEMB * 4);
  float* dinv  = (float*)carve((size_t)N * 4);
  float* dnv2  = (float*)carve((size_t)N * 4);
  int* off     = (int*)carve((size_t)(N + 1) * 4);
  int* histG   = (int*)carve((size_t)256 * nbB * 4);
  int* binOff  = (int*)carve(257 * 4);
  int* pr      = (int*)carve((size_t)E * 4);
  int* bsum    = (int*)carve(256 * 4);
  int* boff    = (int*)carve(256 * 4);
  int* csr     = (int*)carve((size_t)E * 4);
  float* u1    = (float*)carve((size_t)N * 4);
  float* u2    = (float*)carve((size_t)N * 4);
  float* u3    = (float*)carve((size_t)N * 4);
  float* a1    = (float*)carve((size_t)N * 4);
  float* a2    = (float*)carve((size_t)N * 4);
  float* a3    = (float*)carve((size_t)N * 4);
  _Float16* ha = (_Float16*)carve((size_t)NP * DEMB * 2);
  _Float16* hb = (_Float16*)carve((size_t)NP * DEMB * 2);
  (void)ws_size; (void)n_in; (void)out_size;

  // fused weight/bias chain (1 launch)
  kweights<<<130, DEMB, 0, stream>>>(gcn, lin, gb, Rh, cb);

  // binned CSR build (6 launches, fused deg + fused off-finalize)
  khist<<<nbB, 256, 0, stream>>>(ei, histG, E, nbB);
  kbase<<<1, 256, 0, stream>>>(histG, binOff, nbB, E);
  kscatter<<<nbB, 256, 0, stream>>>(ei, histG, pr, E, nbB);
  kscan1<<<NBINS, 256, 0, stream>>>(pr, binOff, off, bsum, dinv, dnv2, N);
  kscan2<<<1, 256, 0, stream>>>(bsum, boff, NBINS, off, N, E);
  kfill2<<<NBINS, 256, 0, stream>>>(pr, binOff, boff, off, csr, N);

  // prescale + 4 chained fp16 aggregations with fused u-chain
  kpre<<<(N * 32 + 255) / 256, 256, 0, stream>>>(x0, dinv, ha, N);
  int nbA = (N * 16 + 255) / 256;
  kagg16<1><<<nbA, 256, 0, stream>>>(ha, csr, off, dnv2, dinv, dinv, u1, a1, hb, N);
  kagg16<1><<<nbA, 256, 0, stream>>>(hb, csr, off, dnv2, dinv, a1, u2, a2, ha, N);
  kagg16<1><<<nbA, 256, 0, stream>>>(ha, csr, off, dnv2, dinv, a2, u3, a3, hb, N);
  kagg16<0><<<nbA, 256, 0, stream>>>(hb, csr, off, dinv, dinv, nullptr, nullptr, nullptr, ha, N);

  // final fp16-MFMA GEMM with rank-1 bias terms -> fp32 out
  kgemm16<<<(N + 127) / 128, 256, 0, stream>>>(ha, Rh, u1, u2, u3, cb, gb + 3 * DEMB, out, N);
}

// Round 12
// 215.470 us; speedup vs baseline: 1.2805x; 1.0114x over previous
//
#include <hip/hip_runtime.h>

#define DEMB 128
#define EB 8192  // edges per block in khist/kscatter

typedef __attribute__((ext_vector_type(8))) _Float16 half8;
typedef __attribute__((ext_vector_type(4))) _Float16 half4;
typedef __attribute__((ext_vector_type(4))) float f32x4;

// ---------- fused weight/bias chain (one launch, 130 blocks x 128 thr)
__global__ void kweights(const float* __restrict__ gcn, const float* __restrict__ lin,
                         const float* __restrict__ gb, _Float16* __restrict__ Rh,
                         float* __restrict__ cb) {
  __shared__ float va[128], vb[128];
  int b = blockIdx.x, j = threadIdx.x;
  const float* G0 = gcn;
  const float* G1 = gcn + 16384;
  const float* G2 = gcn + 2 * 16384;
  const float* G3 = gcn + 3 * 16384;
  const float* L0 = lin;
  const float* L1 = lin + 16384;
  const float* L2 = lin + 2 * 16384;
  const float* L3 = lin + 3 * 16384;
  float* cur = va;
  float* nxt = vb;
  if (b < 128) {
    const float* seq[7] = {L3, G2, L2, G1, L1, G0, L0};
    va[j] = G3[b * 128 + j];
    __syncthreads();
#pragma unroll
    for (int s = 0; s < 7; ++s) {
      const float* M = seq[s];
      float acc = 0.f;
#pragma unroll 8
      for (int k = 0; k < 128; ++k) acc += cur[k] * M[k * 128 + j];
      nxt[j] = acc;
      __syncthreads();
      float* t2 = cur; cur = nxt; nxt = t2;
    }
    Rh[b * 128 + j] = (_Float16)cur[j];
  } else if (b == 128) {
    const float* seq[6] = {L1, G1, L2, G2, L3, G3};
    va[j] = gb[j];
    __syncthreads();
#pragma unroll
    for (int s = 0; s < 6; ++s) {
      const float* M = seq[s];
      float acc = 0.f;
#pragma unroll 8
      for (int k = 0; k < 128; ++k) acc += M[j * 128 + k] * cur[k];
      nxt[j] = acc;
      __syncthreads();
      float* t2 = cur; cur = nxt; nxt = t2;
    }
    cb[j] = cur[j];
  } else {
    const float* seqB[4] = {L2, G2, L3, G3};
    va[j] = gb[128 + j];
    __syncthreads();
#pragma unroll
    for (int s = 0; s < 4; ++s) {
      const float* M = seqB[s];
      float acc = 0.f;
#pragma unroll 8
      for (int k = 0; k < 128; ++k) acc += M[j * 128 + k] * cur[k];
      nxt[j] = acc;
      __syncthreads();
      float* t2 = cur; cur = nxt; nxt = t2;
    }
    cb[128 + j] = cur[j];
    __syncthreads();
    cur[j] = gb[256 + j];
    __syncthreads();
    const float* seqC[2] = {L3, G3};
#pragma unroll
    for (int s = 0; s < 2; ++s) {
      const float* M = seqC[s];
      float acc = 0.f;
#pragma unroll 8
      for (int k = 0; k < 128; ++k) acc += M[j * 128 + k] * cur[k];
      nxt[j] = acc;
      __syncthreads();
      float* t2 = cur; cur = nxt; nxt = t2;
    }
    cb[256 + j] = cur[j];
  }
}

// ---------- binned CSR build ----------
__global__ void khist(const int* __restrict__ ei, int* __restrict__ histG,
                      int etot, int nbB) {
  __shared__ int lh[256];
  int t = threadIdx.x;
  lh[t] = 0;
  __syncthreads();
#pragma unroll 4
  for (int j = 0; j < EB / 256; ++j) {
    int i = blockIdx.x * EB + j * 256 + t;
    if (i < etot) atomicAdd(&lh[ei[etot + i] >> 8], 1);
  }
  __syncthreads();
  histG[t * nbB + blockIdx.x] = lh[t];
}

__global__ void kbase(int* __restrict__ histG, int* __restrict__ binOff,
                      int nbB, int etot) {
  __shared__ int s[256];
  int t = threadIdx.x;
  int* row = histG + t * nbB;
  int tot = 0;
#pragma unroll 4
  for (int b = 0; b < nbB; ++b) tot += row[b];
  s[t] = tot;
  __syncthreads();
  for (int o = 1; o < 256; o <<= 1) {
    int v = (t >= o) ? s[t - o] : 0;
    __syncthreads();
    s[t] += v;
    __syncthreads();
  }
  int bstart = s[t] - tot;
  binOff[t] = bstart;
  if (t == 255) binOff[256] = etot;
  int run = bstart;
#pragma unroll 4
  for (int b = 0; b < nbB; ++b) {
    int v = row[b];
    row[b] = run;
    run += v;
  }
}

__global__ void kscatter(const int* __restrict__ ei, const int* __restrict__ histG,
                         int* __restrict__ pr, int etot, int nbB) {
  __shared__ int cur[256];
  int t = threadIdx.x;
  cur[t] = histG[t * nbB + blockIdx.x];
  __syncthreads();
#pragma unroll 4
  for (int j = 0; j < EB / 256; ++j) {
    int i = blockIdx.x * EB + j * 256 + t;
    if (i < etot) {
      int src = ei[i], dst = ei[etot + i];
      int p = atomicAdd(&cur[dst >> 8], 1);
      pr[p] = (src << 8) | (dst & 255);
    }
  }
}

// kscan1 (fused degree count + dinv + per-bin edge-offset scan)
__global__ void kscan1(const int* __restrict__ pr, const int* __restrict__ binOff,
                       int* __restrict__ off, int* __restrict__ bsum,
                       float* __restrict__ dinv, float* __restrict__ dinv2, int n) {
  __shared__ int dl[256];
  __shared__ int s[256];
  int t = threadIdx.x, b = blockIdx.x;
  dl[t] = 0;
  __syncthreads();
  int s1 = binOff[b + 1];
  for (int p = binOff[b] + t; p < s1; p += 256)
    atomicAdd(&dl[pr[p] & 255], 1);
  __syncthreads();
  int i = b * 256 + t;
  int c = 0;
  if (i < n) {
    c = dl[t];
    float dv = rsqrtf((float)(c + 1));
    dinv[i] = dv;
    dinv2[i] = dv * dv;
  }
  s[t] = c;
  __syncthreads();
  for (int o = 1; o < 256; o <<= 1) {
    int v = (t >= o) ? s[t - o] : 0;
    __syncthreads();
    s[t] += v;
    __syncthreads();
  }
  if (i < n) off[i] = s[t] - c;
  if (t == 255) bsum[b] = s[t];
}

// kfill2 (fused block-sum scan + off-finalize + CSR fill): block b = bin b.
// Each block redundantly scans bsum[0..nb) in LDS to get boff[b] (no kscan2 kernel).
__global__ void kfill2(const int* __restrict__ pr, const int* __restrict__ binOff,
                       const int* __restrict__ bsum, int nb, int* __restrict__ off,
                       int* __restrict__ csr, int n, int etot) {
  __shared__ int s[256];
  __shared__ int cur[256];
  int t = threadIdx.x, b = blockIdx.x;
  // exclusive prefix of bsum up to b
  int c = (t < nb) ? bsum[t] : 0;
  s[t] = c;
  __syncthreads();
  for (int o = 1; o < 256; o <<= 1) {
    int v = (t >= o) ? s[t - o] : 0;
    __syncthreads();
    s[t] += v;
    __syncthreads();
  }
  int boffb = (b > 0) ? s[b - 1] : 0;  // exclusive sum over bins < b
  if (b == 0 && t == 0) off[n] = etot;
  int node = (b << 8) + t;
  int o = 0;
  if (node < n) {
    o = off[node] + boffb;
    off[node] = o;
  }
  cur[t] = o;
  __syncthreads();
  int s1 = binOff[b + 1];
  for (int p = binOff[b] + t; p < s1; p += 256) {
    int v = pr[p];
    int pos = atomicAdd(&cur[v & 255], 1);
    csr[pos] = v >> 8;
  }
}

// ---------- prescale: xh[i][c] = fp16(x[i][c] * dinv[i])
__global__ void kpre(const float* __restrict__ x, const float* __restrict__ dinv,
                     _Float16* __restrict__ xh, int n) {
  int gid = blockIdx.x * 256 + threadIdx.x;
  if (gid >= n * 32) return;
  int r = gid >> 5, c = (gid & 31) * 4;
  float d = dinv[r];
  float4 v = *(const float4*)(x + (size_t)r * DEMB + c);
  half4 o = {(_Float16)(v.x * d), (_Float16)(v.y * d), (_Float16)(v.z * d), (_Float16)(v.w * d)};
  *(half4*)(xh + (size_t)r * DEMB + c) = o;
}

// ---------- fp16 aggregation: quarter-wave (16 lanes) per node, 8/4/tail ladder.
template <int WITHU>
__launch_bounds__(256)
__global__ void kagg16(const _Float16* __restrict__ vin, const int* __restrict__ csr,
                       const int* __restrict__ off, const float* __restrict__ scale,
                       const float* __restrict__ dinv, const float* __restrict__ a_in,
                       float* __restrict__ u_out, float* __restrict__ a_out,
                       _Float16* __restrict__ vout, int n) {
  int node = (int)((blockIdx.x * 256u + threadIdx.x) >> 4);
  if (node >= n) return;
  int l16 = threadIdx.x & 15;
  const _Float16* base = vin + 8 * l16;
  half8 sv = *(const half8*)(base + (size_t)node * DEMB);
  float acc[8];
#pragma unroll
  for (int j = 0; j < 8; ++j) acc[j] = (float)sv[j];
  float s = WITHU ? a_in[node] : 0.f;
  int e = off[node], end = off[node + 1];
  for (; e + 8 <= end; e += 8) {
    int i0 = csr[e], i1 = csr[e + 1], i2 = csr[e + 2], i3 = csr[e + 3];
    int i4 = csr[e + 4], i5 = csr[e + 5], i6 = csr[e + 6], i7 = csr[e + 7];
    half8 r0 = *(const half8*)(base + (size_t)i0 * DEMB);
    half8 r1 = *(const half8*)(base + (size_t)i1 * DEMB);
    half8 r2 = *(const half8*)(base + (size_t)i2 * DEMB);
    half8 r3 = *(const half8*)(base + (size_t)i3 * DEMB);
    half8 r4 = *(const half8*)(base + (size_t)i4 * DEMB);
    half8 r5 = *(const half8*)(base + (size_t)i5 * DEMB);
    half8 r6 = *(const half8*)(base + (size_t)i6 * DEMB);
    half8 r7 = *(const half8*)(base + (size_t)i7 * DEMB);
    if (WITHU)
      s += a_in[i0] + a_in[i1] + a_in[i2] + a_in[i3] +
           a_in[i4] + a_in[i5] + a_in[i6] + a_in[i7];
#pragma unroll
    for (int j = 0; j < 8; ++j)
      acc[j] += ((float)r0[j] + (float)r1[j]) + ((float)r2[j] + (float)r3[j]) +
                ((float)r4[j] + (float)r5[j]) + ((float)r6[j] + (float)r7[j]);
  }
  for (; e + 4 <= end; e += 4) {
    int i0 = csr[e], i1 = csr[e + 1], i2 = csr[e + 2], i3 = csr[e + 3];
    half8 r0 = *(const half8*)(base + (size_t)i0 * DEMB);
    half8 r1 = *(const half8*)(base + (size_t)i1 * DEMB);
    half8 r2 = *(const half8*)(base + (size_t)i2 * DEMB);
    half8 r3 = *(const half8*)(base + (size_t)i3 * DEMB);
    if (WITHU) s += a_in[i0] + a_in[i1] + a_in[i2] + a_in[i3];
#pragma unroll
    for (int j = 0; j < 8; ++j)
      acc[j] += ((float)r0[j] + (float)r1[j]) + ((float)r2[j] + (float)r3[j]);
  }
  if (e < end) {
    int em = end - 1;
    int i0 = csr[e];
    int i1 = csr[min(e + 1, em)];
    int i2 = csr[min(e + 2, em)];
    float w1 = (e + 1 < end) ? 1.f : 0.f;
    float w2 = (e + 2 < end) ? 1.f : 0.f;
    half8 r0 = *(const half8*)(base + (size_t)i0 * DEMB);
    half8 r1 = *(const half8*)(base + (size_t)i1 * DEMB);
    half8 r2 = *(const half8*)(base + (size_t)i2 * DEMB);
    if (WITHU) s += a_in[i0] + w1 * a_in[i1] + w2 * a_in[i2];
#pragma unroll
    for (int j = 0; j < 8; ++j)
      acc[j] += (float)r0[j] + w1 * (float)r1[j] + w2 * (float)r2[j];
  }
  float sc = scale[node];
  half8 o;
#pragma unroll
  for (int j = 0; j < 8; ++j) o[j] = (_Float16)(acc[j] * sc);
  *(half8*)(vout + (size_t)node * DEMB + 8 * l16) = o;
  if (WITHU && l16 == 0) {
    float dv = dinv[node];
    float u = dv * s;
    u_out[node] = u;
    a_out[node] = dv * u;
  }
}

// ---------- final MFMA GEMM
__launch_bounds__(256)
__global__ void kgemm16(const _Float16* __restrict__ y, const _Float16* __restrict__ Rh,
                        const float* __restrict__ u1, const float* __restrict__ u2,
                        const float* __restrict__ u3, const float* __restrict__ cb,
                        const float* __restrict__ b3, float* __restrict__ out, int n) {
  int t = threadIdx.x;
  int wv = t >> 6, lane = t & 63;
  int l16 = lane & 15, g = lane >> 4;
  int row0 = blockIdx.x * 128 + wv * 32;
  f32x4 acc[2][8];
#pragma unroll
  for (int w = 0; w < 2; ++w)
#pragma unroll
    for (int n8 = 0; n8 < 8; ++n8) acc[w][n8] = (f32x4){0.f, 0.f, 0.f, 0.f};

#pragma unroll
  for (int k0 = 0; k0 < 128; k0 += 32) {
    half8 a0 = *(const half8*)(y + (size_t)(row0 + l16) * DEMB + k0 + g * 8);
    half8 a1 = *(const half8*)(y + (size_t)(row0 + 16 + l16) * DEMB + k0 + g * 8);
#pragma unroll
    for (int n8 = 0; n8 < 8; ++n8) {
      half8 b = *(const half8*)(Rh + (size_t)(n8 * 16 + l16) * DEMB + k0 + g * 8);
      acc[0][n8] = __builtin_amdgcn_mfma_f32_16x16x32_f16(a0, b, acc[0][n8], 0, 0, 0);
      acc[1][n8] = __builtin_amdgcn_mfma_f32_16x16x32_f16(a1, b, acc[1][n8], 0, 0, 0);
    }
  }
#pragma unroll
  for (int n8 = 0; n8 < 8; ++n8) {
    int col = n8 * 16 + l16;
    float cA = cb[col], cB = cb[128 + col], cC = cb[256 + col], bb = b3[col];
#pragma unroll
    for (int w = 0; w < 2; ++w)
#pragma unroll
      for (int r = 0; r < 4; ++r) {
        int row = row0 + w * 16 + g * 4 + r;
        if (row < n) {
          out[(size_t)row * DEMB + col] =
              acc[w][n8][r] + u3[row] * cA + u2[row] * cB + u1[row] * cC + bb;
        }
      }
  }
}

extern "C" void kernel_launch(void* const* d_in, const int* in_sizes, int n_in,
                              void* d_out, int out_size, void* d_ws, size_t ws_size,
                              hipStream_t stream) {
  const float* x0 = (const float*)d_in[0];
  const int* ei = (const int*)d_in[1];
  const float* lin = (const float*)d_in[2];
  const float* gcn = (const float*)d_in[3];
  const float* gb = (const float*)d_in[4];
  float* out = (float*)d_out;

  int N = in_sizes[0] / DEMB;
  int E = in_sizes[1] / 2;
  int NP = (N + 127) & ~127;
  int NBINS = (N + 255) >> 8;           // 196
  int nbB = (E + EB - 1) / EB;          // 74

  char* w = (char*)d_ws;
  auto carve = [&](size_t bytes) {
    char* p = w;
    w += (bytes + 255) & ~(size_t)255;
    return p;
  };
  _Float16* Rh = (_Float16*)carve((size_t)DEMB * DEMB * 2);
  float* cb    = (float*)carve((size_t)3 * DEMB * 4);
  float* dinv  = (float*)carve((size_t)N * 4);
  float* dnv2  = (float*)carve((size_t)N * 4);
  int* off     = (int*)carve((size_t)(N + 1) * 4);
  int* histG   = (int*)carve((size_t)256 * nbB * 4);
  int* binOff  = (int*)carve(257 * 4);
  int* pr      = (int*)carve((size_t)E * 4);
  int* bsum    = (int*)carve(256 * 4);
  int* csr     = (int*)carve((size_t)E * 4);
  float* u1    = (float*)carve((size_t)N * 4);
  float* u2    = (float*)carve((size_t)N * 4);
  float* u3    = (float*)carve((size_t)N * 4);
  float* a1    = (float*)carve((size_t)N * 4);
  float* a2    = (float*)carve((size_t)N * 4);
  float* a3    = (float*)carve((size_t)N * 4);
  _Float16* ha = (_Float16*)carve((size_t)NP * DEMB * 2);
  _Float16* hb = (_Float16*)carve((size_t)NP * DEMB * 2);
  (void)ws_size; (void)n_in; (void)out_size;

  // fused weight/bias chain (1 launch)
  kweights<<<130, DEMB, 0, stream>>>(gcn, lin, gb, Rh, cb);

  // binned CSR build (5 launches)
  khist<<<nbB, 256, 0, stream>>>(ei, histG, E, nbB);
  kbase<<<1, 256, 0, stream>>>(histG, binOff, nbB, E);
  kscatter<<<nbB, 256, 0, stream>>>(ei, histG, pr, E, nbB);
  kscan1<<<NBINS, 256, 0, stream>>>(pr, binOff, off, bsum, dinv, dnv2, N);
  kfill2<<<NBINS, 256, 0, stream>>>(pr, binOff, bsum, NBINS, off, csr, N, E);

  // prescale + 4 chained fp16 aggregations with fused u-chain
  kpre<<<(N * 32 + 255) / 256, 256, 0, stream>>>(x0, dinv, ha, N);
  int nbA = (N * 16 + 255) / 256;
  kagg16<1><<<nbA, 256, 0, stream>>>(ha, csr, off, dnv2, dinv, dinv, u1, a1, hb, N);
  kagg16<1><<<nbA, 256, 0, stream>>>(hb, csr, off, dnv2, dinv, a1, u2, a2, ha, N);
  kagg16<1><<<nbA, 256, 0, stream>>>(ha, csr, off, dnv2, dinv, a2, u3, a3, hb, N);
  kagg16<0><<<nbA, 256, 0, stream>>>(hb, csr, off, dinv, dinv, nullptr, nullptr, nullptr, ha, N);

  // final fp16-MFMA GEMM with rank-1 bias terms -> fp32 out
  kgemm16<<<(N + 127) / 128, 256, 0, stream>>>(ha, Rh, u1, u2, u3, cb, gb + 3 * DEMB, out, N);
}